// Round 13
// baseline (759.805 us; speedup 1.0000x reference)
//
#include <hip/hip_runtime.h>
#include <hip/hip_bf16.h>
#include <stdint.h>

// Router GEMM: out[8192,768] (fp32) = X[8192,6144] @ W[768,6144]^T
// Device buffers hold FP32 upcasts of the bf16 data (round-6 discovery).
// Round 13: STRUCTURE change — W-stationary-in-LDS, X register-direct,
// barrier-light. r8-r12 showed the 2-barrier-per-K-step lockstep structure
// pins MfmaUtil at 13% no matter the tuning (TLP/prefetch/conflicts all
// ruled out). Here: 2 barriers per 192-k chunk (6 k-steps), B-frags from
// read-only LDS, A-frags per-lane from global (L1/L2), waves run free.
//   - block: 256 m x 128 n x 1536 k; 8 waves, wave-tile 32x128
//   - LDS: W-slice [128][192] bf16, row-padded to 26 16B-units (bank-free
//     column reads: 26*lrow mod 32 spans all 16 even quads)
//   - grid 768 = 8 XCD x (bn fastest) -> 6 bn-blocks sharing X co-resident
//     per XCD; 3 blocks/CU (LDS 3x52KB=156<=160), 24 waves/CU
//   - SK=4 + memset + relaxed atomic-add epilogue (r8-proven)

#define M_DIM 8192
#define N_DIM 768
#define K_DIM 6144

#define BNP    128                 // n-cols per block
#define SPLITK 4
#define KSEG   (K_DIM / SPLITK)    // 1536
#define CHUNK  192                 // k per LDS-resident W slice
#define NCHUNK (KSEG / CHUNK)      // 8
#define KSTEPS (CHUNK / 32)        // 6
#define CPAD   26                  // padded row stride in 16B units (from 24)

typedef __bf16 bf16x8 __attribute__((ext_vector_type(8)));
typedef float f32x4 __attribute__((ext_vector_type(4)));

static __device__ __forceinline__ __bf16 bf16_trunc(float f) {
    uint32_t u = __builtin_bit_cast(uint32_t, f);
    return __builtin_bit_cast(__bf16, (uint16_t)(u >> 16));  // exact on upcast data
}

static __device__ __forceinline__ bf16x8 pack_bf16x8(f32x4 a, f32x4 b) {
    bf16x8 r;
    #pragma unroll
    for (int j = 0; j < 4; ++j) {
        r[j]     = bf16_trunc(a[j]);
        r[4 + j] = bf16_trunc(b[j]);
    }
    return r;
}

__global__ __launch_bounds__(512, 6) void router_gemm_wstat_kernel(
    const float* __restrict__ X, const float* __restrict__ W,
    float* __restrict__ out)
{
    // W-slice: [128 rows][CPAD units][8 bf16] = 53248 B (52 KiB)
    __shared__ __align__(16) __bf16 Bs[128 * CPAD * 8];

    const int tid  = threadIdx.x;
    const int w    = tid >> 6;             // wave 0..7
    const int lane = tid & 63;
    const int lrow = lane & 15;            // fragment index field
    const int kg   = lane >> 4;            // fragment k-group

    // block decode: xcd round-robin; within XCD bn fastest so the 6 blocks
    // sharing an X-slice are co-resident on one XCD (L2 multiplies X reads).
    const int xcd  = blockIdx.x & 7;
    const int slot = blockIdx.x >> 3;      // 0..95
    const int bn   = slot % 6;
    const int gs   = slot / 6;             // 0..15
    const int sk   = gs & 3;               // 0..3
    const int gm   = xcd * 4 + (gs >> 2);  // 0..31

    const int kbase = sk * KSEG;
    const int m0    = gm * 256 + w * 32;   // wave's 32 m-rows

    // A: per-lane row-fixed pointers (rows m0+lrow and m0+16+lrow)
    const float* xp0 = X + (size_t)(m0 + lrow) * K_DIM + kg * 8;
    const float* xp1 = xp0 + (size_t)16 * K_DIM;

    // W staging decode: thread t -> row t>>2, c-units (t&3)*6 .. +5
    const int swr = tid >> 2;              // 0..127
    const int scu = (tid & 3) * 6;
    const float* wp = W + (size_t)(bn * BNP + swr) * K_DIM + scu * 8;
    __bf16* sbase = Bs + ((size_t)swr * CPAD + scu) * 8;

    // B-frag read base: row nf*16+lrow, unit c8 = ks*4+kg
    const __bf16* rbase = Bs + ((size_t)lrow * CPAD + kg) * 8;

    f32x4 acc[2][8] = {};

    for (int c = 0; c < NCHUNK; ++c) {
        const int kc = kbase + c * CHUNK;
        __syncthreads();                   // prior chunk's B reads done
        #pragma unroll
        for (int j = 0; j < 6; ++j) {
            f32x4 lo = *(const f32x4*)(wp + kc + j * 8);
            f32x4 hi = *(const f32x4*)(wp + kc + j * 8 + 4);
            *(bf16x8*)(sbase + j * 8) = pack_bf16x8(lo, hi);
        }
        __syncthreads();                   // slice staged

        #pragma unroll
        for (int ks = 0; ks < KSTEPS; ++ks) {
            const int k = kc + ks * 32;
            // A fragments: global fp32 -> bf16 (exact truncation)
            f32x4 a00 = *(const f32x4*)(xp0 + k);
            f32x4 a01 = *(const f32x4*)(xp0 + k + 4);
            f32x4 a10 = *(const f32x4*)(xp1 + k);
            f32x4 a11 = *(const f32x4*)(xp1 + k + 4);
            bf16x8 af0 = pack_bf16x8(a00, a01);
            bf16x8 af1 = pack_bf16x8(a10, a11);
            // B fragments from read-only LDS (pad-26 -> 2 lanes/quad, free)
            bf16x8 bf[8];
            #pragma unroll
            for (int nf = 0; nf < 8; ++nf)
                bf[nf] = *(const bf16x8*)(rbase
                            + ((size_t)nf * 16 * CPAD + ks * 4) * 8);
            #pragma unroll
            for (int nf = 0; nf < 8; ++nf) {
                acc[0][nf] = __builtin_amdgcn_mfma_f32_16x16x32_bf16(
                    af0, bf[nf], acc[0][nf], 0, 0, 0);
                acc[1][nf] = __builtin_amdgcn_mfma_f32_16x16x32_bf16(
                    af1, bf[nf], acc[1][nf], 0, 0, 0);
            }
        }
    }

    // epilogue: relaxed device-scope fp32 atomic add (out zeroed in launch).
    // C/D layout: col = lane&15, row = (lane>>4)*4 + reg (verified).
    const int orow0 = m0 + kg * 4;
    const int ocol0 = bn * BNP + lrow;
    #pragma unroll
    for (int mf = 0; mf < 2; ++mf)
        #pragma unroll
        for (int nf = 0; nf < 8; ++nf)
            #pragma unroll
            for (int r = 0; r < 4; ++r) {
                float* o = out + (size_t)(orow0 + mf * 16 + r) * N_DIM
                               + (ocol0 + nf * 16);
                __hip_atomic_fetch_add(o, acc[mf][nf][r],
                                       __ATOMIC_RELAXED, __HIP_MEMORY_SCOPE_AGENT);
            }
}

extern "C" void kernel_launch(void* const* d_in, const int* in_sizes, int n_in,
                              void* d_out, int out_size, void* d_ws, size_t ws_size,
                              hipStream_t stream) {
    const float* X;
    const float* W;
    if (in_sizes[0] == M_DIM * K_DIM) {
        X = (const float*)d_in[0];
        W = (const float*)d_in[1];
    } else {
        X = (const float*)d_in[1];
        W = (const float*)d_in[0];
    }
    float* out = (float*)d_out;

    // zero-init for atomic accumulation (async stream op: graph-capture-safe)
    hipMemsetAsync(out, 0, (size_t)M_DIM * N_DIM * sizeof(float), stream);

    const int grid = 8 * 96;   // 32 gm x 6 bn x 4 sk = 768 blocks, 3/CU
    hipLaunchKernelGGL(router_gemm_wstat_kernel, dim3(grid), dim3(512), 0, stream,
                       X, W, out);
}

// Round 14
// 376.552 us; speedup vs baseline: 2.0178x; 2.0178x over previous
//
#include <hip/hip_runtime.h>
#include <hip/hip_bf16.h>
#include <stdint.h>

// Router GEMM: out[8192,768] (fp32) = X[8192,6144] @ W[768,6144]^T
// Device buffers hold FP32 upcasts of the bf16 data (round-6 discovery).
// Round 14: r13's W-stationary structure RETESTED with correct register
// budget. r13's __launch_bounds__(512,6) forced VGPR cap 85 < ~120 needed ->
// acc spilled to scratch (VGPR_Count 40, WRITE 1.49GB, 760us). One change:
// __launch_bounds__(512,4) -> cap 128, 2 blocks/CU, 16 waves/CU, no spill.
//   - block: 256 m x 128 n x 1536 k; 8 waves, wave-tile 32x128
//   - W-slice [128][192] bf16 in LDS, row stride padded to 26 16B-units
//   - 2 barriers per 192-k chunk; A-frags per-lane from global (fp32->bf16)
//   - grid 768, bn fastest within XCD (X sharers co-resident), SK=4 atomics

#define M_DIM 8192
#define N_DIM 768
#define K_DIM 6144

#define BNP    128                 // n-cols per block
#define SPLITK 4
#define KSEG   (K_DIM / SPLITK)    // 1536
#define CHUNK  192                 // k per LDS-resident W slice
#define NCHUNK (KSEG / CHUNK)      // 8
#define KSTEPS (CHUNK / 32)        // 6
#define CPAD   26                  // padded row stride in 16B units

typedef __bf16 bf16x8 __attribute__((ext_vector_type(8)));
typedef float f32x4 __attribute__((ext_vector_type(4)));

static __device__ __forceinline__ __bf16 bf16_trunc(float f) {
    uint32_t u = __builtin_bit_cast(uint32_t, f);
    return __builtin_bit_cast(__bf16, (uint16_t)(u >> 16));  // exact on upcast data
}

static __device__ __forceinline__ bf16x8 pack_bf16x8(f32x4 a, f32x4 b) {
    bf16x8 r;
    #pragma unroll
    for (int j = 0; j < 4; ++j) {
        r[j]     = bf16_trunc(a[j]);
        r[4 + j] = bf16_trunc(b[j]);
    }
    return r;
}

__global__ __launch_bounds__(512, 4) void router_gemm_wstat4_kernel(
    const float* __restrict__ X, const float* __restrict__ W,
    float* __restrict__ out)
{
    // W-slice: [128 rows][CPAD units][8 bf16] = 53248 B (52 KiB)
    __shared__ __align__(16) __bf16 Bs[128 * CPAD * 8];

    const int tid  = threadIdx.x;
    const int w    = tid >> 6;             // wave 0..7
    const int lane = tid & 63;
    const int lrow = lane & 15;            // fragment index field
    const int kg   = lane >> 4;            // fragment k-group

    // block decode: xcd round-robin; bn fastest within XCD so the 6 blocks
    // sharing an X-slice are co-resident on one XCD (L2 multiplies X reads).
    const int xcd  = blockIdx.x & 7;
    const int slot = blockIdx.x >> 3;      // 0..95
    const int bn   = slot % 6;
    const int gs   = slot / 6;             // 0..15
    const int sk   = gs & 3;               // 0..3
    const int gm   = xcd * 4 + (gs >> 2);  // 0..31

    const int kbase = sk * KSEG;
    const int m0    = gm * 256 + w * 32;   // wave's 32 m-rows

    // A: per-lane row-fixed pointers (rows m0+lrow and m0+16+lrow)
    const float* xp0 = X + (size_t)(m0 + lrow) * K_DIM + kg * 8;
    const float* xp1 = xp0 + (size_t)16 * K_DIM;

    // W staging decode: thread t -> row t>>2, c-units (t&3)*6 .. +5
    const int swr = tid >> 2;              // 0..127
    const int scu = (tid & 3) * 6;
    const float* wp = W + (size_t)(bn * BNP + swr) * K_DIM + scu * 8;
    __bf16* sbase = Bs + ((size_t)swr * CPAD + scu) * 8;

    // B-frag read base: row nf*16+lrow, unit ks*4+kg
    const __bf16* rbase = Bs + ((size_t)lrow * CPAD + kg) * 8;

    f32x4 acc[2][8] = {};

    for (int c = 0; c < NCHUNK; ++c) {
        const int kc = kbase + c * CHUNK;
        __syncthreads();                   // prior chunk's B reads done
        #pragma unroll
        for (int j = 0; j < 6; ++j) {
            f32x4 lo = *(const f32x4*)(wp + kc + j * 8);
            f32x4 hi = *(const f32x4*)(wp + kc + j * 8 + 4);
            *(bf16x8*)(sbase + j * 8) = pack_bf16x8(lo, hi);
        }
        __syncthreads();                   // slice staged

        #pragma unroll
        for (int ks = 0; ks < KSTEPS; ++ks) {
            const int k = kc + ks * 32;
            // A fragments: global fp32 -> bf16 (exact truncation)
            f32x4 a00 = *(const f32x4*)(xp0 + k);
            f32x4 a01 = *(const f32x4*)(xp0 + k + 4);
            f32x4 a10 = *(const f32x4*)(xp1 + k);
            f32x4 a11 = *(const f32x4*)(xp1 + k + 4);
            bf16x8 af0 = pack_bf16x8(a00, a01);
            bf16x8 af1 = pack_bf16x8(a10, a11);
            // B fragments from read-only LDS (pad-26 column reads: free)
            bf16x8 bf[8];
            #pragma unroll
            for (int nf = 0; nf < 8; ++nf)
                bf[nf] = *(const bf16x8*)(rbase
                            + ((size_t)nf * 16 * CPAD + ks * 4) * 8);
            #pragma unroll
            for (int nf = 0; nf < 8; ++nf) {
                acc[0][nf] = __builtin_amdgcn_mfma_f32_16x16x32_bf16(
                    af0, bf[nf], acc[0][nf], 0, 0, 0);
                acc[1][nf] = __builtin_amdgcn_mfma_f32_16x16x32_bf16(
                    af1, bf[nf], acc[1][nf], 0, 0, 0);
            }
        }
    }

    // epilogue: relaxed device-scope fp32 atomic add (out zeroed in launch).
    // C/D layout: col = lane&15, row = (lane>>4)*4 + reg (verified).
    const int orow0 = m0 + kg * 4;
    const int ocol0 = bn * BNP + lrow;
    #pragma unroll
    for (int mf = 0; mf < 2; ++mf)
        #pragma unroll
        for (int nf = 0; nf < 8; ++nf)
            #pragma unroll
            for (int r = 0; r < 4; ++r) {
                float* o = out + (size_t)(orow0 + mf * 16 + r) * N_DIM
                               + (ocol0 + nf * 16);
                __hip_atomic_fetch_add(o, acc[mf][nf][r],
                                       __ATOMIC_RELAXED, __HIP_MEMORY_SCOPE_AGENT);
            }
}

extern "C" void kernel_launch(void* const* d_in, const int* in_sizes, int n_in,
                              void* d_out, int out_size, void* d_ws, size_t ws_size,
                              hipStream_t stream) {
    const float* X;
    const float* W;
    if (in_sizes[0] == M_DIM * K_DIM) {
        X = (const float*)d_in[0];
        W = (const float*)d_in[1];
    } else {
        X = (const float*)d_in[1];
        W = (const float*)d_in[0];
    }
    float* out = (float*)d_out;

    // zero-init for atomic accumulation (async stream op: graph-capture-safe)
    hipMemsetAsync(out, 0, (size_t)M_DIM * N_DIM * sizeof(float), stream);

    const int grid = 8 * 96;   // 32 gm x 6 bn x 4 sk = 768 blocks, 2/CU resident
    hipLaunchKernelGGL(router_gemm_wstat4_kernel, dim3(grid), dim3(512), 0, stream,
                       X, W, out);
}

// Round 15
// 178.859 us; speedup vs baseline: 4.2481x; 2.1053x over previous
//
#include <hip/hip_runtime.h>
#include <hip/hip_bf16.h>
#include <stdint.h>

// Router GEMM: out[8192,768] (fp32) = X[8192,6144] @ W[768,6144]^T
// Device buffers hold FP32 upcasts of the bf16 data (round-6 discovery).
// Round 15: attack r8's real critical path (barrier/vmcnt chain per tiny
// K-step): double-buffered LDS + ONE barrier per K-step + BK=64.
//   schedule/iter: {ISSUE loads(t+1) -> COMPUTE(buf) -> WRITE(buf^1) -> bar}
//   issue-to-wait distance = full compute phase (~310cy MFMA + reads).
//   Barriers per block: 192 (r8) -> 24.
//   256 thr / 4 waves (2x2 of 64x64), BM=BN=128, SK=4, XCD-local X panels,
//   swizzle slot=ku^(row&7) (reads 8 lanes/quad = b128 optimum), atomics.
//   Budget: acc 64 + pr 64 + frags 32 + ptrs ~20 ~= 200 < 256 cap at (256,2).

#define M_DIM 8192
#define N_DIM 768
#define K_DIM 6144

#define BM 128
#define BN 128
#define BK 64
#define SPLITK 4
#define KSEG (K_DIM / SPLITK)    // 1536
#define NT (KSEG / BK)           // 24 K-steps (even)

typedef __bf16 bf16x8 __attribute__((ext_vector_type(8)));
typedef float f32x4 __attribute__((ext_vector_type(4)));

static __device__ __forceinline__ __bf16 bf16_trunc(float f) {
    uint32_t u = __builtin_bit_cast(uint32_t, f);
    return __builtin_bit_cast(__bf16, (uint16_t)(u >> 16));  // exact on upcast data
}

static __device__ __forceinline__ bf16x8 pack_bf16x8(f32x4 a, f32x4 b) {
    bf16x8 r;
    #pragma unroll
    for (int j = 0; j < 4; ++j) {
        r[j]     = bf16_trunc(a[j]);
        r[4 + j] = bf16_trunc(b[j]);
    }
    return r;
}

__global__ __launch_bounds__(256, 2) void router_gemm_db64_kernel(
    const float* __restrict__ X, const float* __restrict__ W,
    float* __restrict__ out)
{
    // double-buffered tiles [buf][128 rows][64 k] bf16 (16 KiB each)
    __shared__ __align__(16) __bf16 As[2][BM * BK];
    __shared__ __align__(16) __bf16 Bs[2][BN * BK];

    const int tid  = threadIdx.x;
    const int w    = tid >> 6;             // wave 0..3
    const int lane = tid & 63;

    // XCD decode: XCD x owns {bmi 0..7} x {bn 0..5} x {ks 0..3};
    // bm = x*8+bmi -> each X panel is XCD-local (L2 multiplies re-reads).
    const int xcd  = blockIdx.x & 7;
    const int slot = blockIdx.x >> 3;      // 0..191
    const int bmi  = slot & 7;
    const int tt   = slot >> 3;            // 0..23
    const int bn   = tt % 6;
    const int ks   = tt / 6;               // 0..3
    const int bm   = xcd * 8 + bmi;        // 0..63

    const int kbase = ks * KSEG;

    const int wr = w >> 1;                 // wave row 0..1 (64 m)
    const int wc = w & 1;                  // wave col 0..1 (64 n)

    const int lrow = lane & 15;
    const int kg   = lane >> 4;

    // staging decode: thread t, sub i=0..3 -> row = i*32 + (t>>3), ku = t&7
    // (8 threads cover one row's 64 k = 256B fp32 contiguous)
    const int srow = tid >> 3;             // 0..31
    const int sku  = tid & 7;              // k-unit 0..7
    // swizzled unit slot: ku ^ (row&7); row&7 == srow&7 (i*32 = 0 mod 8)
    const int wslot = (sku ^ (srow & 7)) * 8;   // element offset in row

    const float* xp0 = X + (size_t)(bm * BM + srow) * K_DIM + sku * 8;
    const float* xp1 = xp0 + (size_t)32 * K_DIM;
    const float* xp2 = xp0 + (size_t)64 * K_DIM;
    const float* xp3 = xp0 + (size_t)96 * K_DIM;
    const float* wp0 = W + (size_t)(bn * BN + srow) * K_DIM + sku * 8;
    const float* wp1 = wp0 + (size_t)32 * K_DIM;
    const float* wp2 = wp0 + (size_t)64 * K_DIM;
    const float* wp3 = wp0 + (size_t)96 * K_DIM;

    f32x4 pr[16];

    #define ISSUE(K0)                                   \
        do {                                            \
            pr[0]  = *(const f32x4*)(xp0 + (K0));       \
            pr[1]  = *(const f32x4*)(xp0 + (K0) + 4);   \
            pr[2]  = *(const f32x4*)(xp1 + (K0));       \
            pr[3]  = *(const f32x4*)(xp1 + (K0) + 4);   \
            pr[4]  = *(const f32x4*)(xp2 + (K0));       \
            pr[5]  = *(const f32x4*)(xp2 + (K0) + 4);   \
            pr[6]  = *(const f32x4*)(xp3 + (K0));       \
            pr[7]  = *(const f32x4*)(xp3 + (K0) + 4);   \
            pr[8]  = *(const f32x4*)(wp0 + (K0));       \
            pr[9]  = *(const f32x4*)(wp0 + (K0) + 4);   \
            pr[10] = *(const f32x4*)(wp1 + (K0));       \
            pr[11] = *(const f32x4*)(wp1 + (K0) + 4);   \
            pr[12] = *(const f32x4*)(wp2 + (K0));       \
            pr[13] = *(const f32x4*)(wp2 + (K0) + 4);   \
            pr[14] = *(const f32x4*)(wp3 + (K0));       \
            pr[15] = *(const f32x4*)(wp3 + (K0) + 4);   \
        } while (0)

    #define WRITE_LDS(BUF)                                                        \
        do {                                                                      \
            _Pragma("unroll")                                                     \
            for (int i = 0; i < 4; ++i) {                                         \
                *(bf16x8*)(As[BUF] + (i * 32 + srow) * BK + wslot) =              \
                    pack_bf16x8(pr[2 * i], pr[2 * i + 1]);                        \
                *(bf16x8*)(Bs[BUF] + (i * 32 + srow) * BK + wslot) =              \
                    pack_bf16x8(pr[8 + 2 * i], pr[8 + 2 * i + 1]);                \
            }                                                                     \
        } while (0)

    f32x4 acc[4][4] = {};

    const int arow0 = wr * 64 + lrow;
    const int brow0 = wc * 64 + lrow;

    #define COMPUTE(BUF)                                                          \
        do {                                                                      \
            _Pragma("unroll")                                                     \
            for (int ksub = 0; ksub < 2; ++ksub) {                                \
                const int rslot = ((ksub * 4 + kg) ^ (lrow & 7)) * 8;             \
                bf16x8 a[4], b[4];                                                \
                _Pragma("unroll")                                                 \
                for (int mf = 0; mf < 4; ++mf)                                    \
                    a[mf] = *(const bf16x8*)(As[BUF]                              \
                                + (arow0 + mf * 16) * BK + rslot);                \
                _Pragma("unroll")                                                 \
                for (int nf = 0; nf < 4; ++nf)                                    \
                    b[nf] = *(const bf16x8*)(Bs[BUF]                              \
                                + (brow0 + nf * 16) * BK + rslot);                \
                _Pragma("unroll")                                                 \
                for (int mf = 0; mf < 4; ++mf)                                    \
                    _Pragma("unroll")                                             \
                    for (int nf = 0; nf < 4; ++nf)                                \
                        acc[mf][nf] = __builtin_amdgcn_mfma_f32_16x16x32_bf16(    \
                            a[mf], b[nf], acc[mf][nf], 0, 0, 0);                  \
            }                                                                     \
        } while (0)

    // prologue: stage tile 0 into buf0
    ISSUE(kbase);
    WRITE_LDS(0);
    __syncthreads();

    for (int t = 0; t < NT; t += 2) {
        // compute buf0(t); stage buf1 <- t+1
        if (t + 1 < NT) ISSUE(kbase + (t + 1) * BK);
        COMPUTE(0);
        if (t + 1 < NT) WRITE_LDS(1);     // waits pr loads issued pre-COMPUTE
        __syncthreads();                   // ONE barrier per K-step
        // compute buf1(t+1); stage buf0 <- t+2
        if (t + 2 < NT) ISSUE(kbase + (t + 2) * BK);
        COMPUTE(1);
        if (t + 2 < NT) WRITE_LDS(0);
        __syncthreads();
    }

    // epilogue: relaxed device-scope fp32 atomic add (out zeroed in launch).
    // C/D layout: col = lane&15, row = (lane>>4)*4 + reg (verified).
    const int orow0 = bm * BM + wr * 64 + kg * 4;
    const int ocol0 = bn * BN + wc * 64 + lrow;
    #pragma unroll
    for (int mf = 0; mf < 4; ++mf)
        #pragma unroll
        for (int nf = 0; nf < 4; ++nf)
            #pragma unroll
            for (int r = 0; r < 4; ++r) {
                float* o = out + (size_t)(orow0 + mf * 16 + r) * N_DIM
                               + (ocol0 + nf * 16);
                __hip_atomic_fetch_add(o, acc[mf][nf][r],
                                       __ATOMIC_RELAXED, __HIP_MEMORY_SCOPE_AGENT);
            }

    #undef ISSUE
    #undef WRITE_LDS
    #undef COMPUTE
}

extern "C" void kernel_launch(void* const* d_in, const int* in_sizes, int n_in,
                              void* d_out, int out_size, void* d_ws, size_t ws_size,
                              hipStream_t stream) {
    const float* X;
    const float* W;
    if (in_sizes[0] == M_DIM * K_DIM) {
        X = (const float*)d_in[0];
        W = (const float*)d_in[1];
    } else {
        X = (const float*)d_in[1];
        W = (const float*)d_in[0];
    }
    float* out = (float*)d_out;

    // zero-init for atomic accumulation (async stream op: graph-capture-safe)
    hipMemsetAsync(out, 0, (size_t)M_DIM * N_DIM * sizeof(float), stream);

    const int grid = (M_DIM / BM) * (N_DIM / BN) * SPLITK;   // 64*6*4 = 1536
    hipLaunchKernelGGL(router_gemm_db64_kernel, dim3(grid), dim3(256), 0, stream,
                       X, W, out);
}